// Round 11
// baseline (194.484 us; speedup 1.0000x reference)
//
#include <hip/hip_runtime.h>

#define C 128
#define K 27
#define BATCHES 4
#define RA_BPB 512            // stage-A blocks per batch
#define CONV_BLOCKS 512
#define CONV_TPB 1024
#define NWAVES_CONV (CONV_BLOCKS * (CONV_TPB / 64))   // 8192
#define BN_EPS 1e-5f

typedef __attribute__((ext_vector_type(2))) __fp16 h2;
typedef __attribute__((ext_vector_type(8))) __fp16 h8;

// ---------------------------------------------------------------- stage A reduce + mask dtype probe
__global__ __launch_bounds__(256) void reduceA_kernel(
    const float* __restrict__ feats, float* __restrict__ psum,
    float* __restrict__ pmax, const unsigned int* __restrict__ mwords,
    int* __restrict__ flag, int NPER) {
  int base = blockIdx.x * 512;
  bool bad = false;
  bad |= (mwords[base + threadIdx.x] > 1u);
  bad |= (mwords[base + 256 + threadIdx.x] > 1u);
  if (__any(bad) && (threadIdx.x & 63) == 0) atomicOr(flag, 1);

  int b = blockIdx.x / RA_BPB, chunk = blockIdx.x % RA_BPB;
  int CH = (NPER + RA_BPB - 1) / RA_BPB;
  int r0 = b * NPER + chunk * CH;
  int r1 = min(b * NPER + NPER, r0 + CH);
  int g = threadIdx.x >> 5;   // 8 row groups
  int l = threadIdx.x & 31;   // lane -> channels 4l..4l+3
  float4 s = make_float4(0.f, 0.f, 0.f, 0.f);
  float4 m = make_float4(-INFINITY, -INFINITY, -INFINITY, -INFINITY);
  int i = r0 + g;
  for (; i + 8 < r1; i += 16) {
    float4 v1 = *(const float4*)(feats + (size_t)i * C + l * 4);
    float4 v2 = *(const float4*)(feats + (size_t)(i + 8) * C + l * 4);
    s.x += v1.x + v2.x; s.y += v1.y + v2.y;
    s.z += v1.z + v2.z; s.w += v1.w + v2.w;
    m.x = fmaxf(m.x, fmaxf(v1.x, v2.x)); m.y = fmaxf(m.y, fmaxf(v1.y, v2.y));
    m.z = fmaxf(m.z, fmaxf(v1.z, v2.z)); m.w = fmaxf(m.w, fmaxf(v1.w, v2.w));
  }
  if (i < r1) {
    float4 v = *(const float4*)(feats + (size_t)i * C + l * 4);
    s.x += v.x; s.y += v.y; s.z += v.z; s.w += v.w;
    m.x = fmaxf(m.x, v.x); m.y = fmaxf(m.y, v.y);
    m.z = fmaxf(m.z, v.z); m.w = fmaxf(m.w, v.w);
  }
  __shared__ float ssum[8][C], smax[8][C];
  *(float4*)&ssum[g][l * 4] = s;
  *(float4*)&smax[g][l * 4] = m;
  __syncthreads();
  if (threadIdx.x < C) {
    int c = threadIdx.x;
    float S = 0.f, M = -INFINITY;
#pragma unroll
    for (int gg = 0; gg < 8; ++gg) {
      S += ssum[gg][c];
      M = fmaxf(M, smax[gg][c]);
    }
    psum[(size_t)blockIdx.x * C + c] = S;
    pmax[(size_t)blockIdx.x * C + c] = M;
  }
}

// ---------------------------------------------------------------- stage B + channel MLP (fused)
__global__ __launch_bounds__(256) void reduceB_mlp_kernel(
    const float* __restrict__ psum, const float* __restrict__ pmax,
    const float* __restrict__ w1, const float* __restrict__ b1,
    const float* __restrict__ w2, const float* __restrict__ b2,
    float* __restrict__ wgt, int NPER) {
  int b = blockIdx.x;
  int g = threadIdx.x >> 5, l = threadIdx.x & 31;
  float4 s = make_float4(0.f, 0.f, 0.f, 0.f);
  float4 m = make_float4(-INFINITY, -INFINITY, -INFINITY, -INFINITY);
  for (int j = g; j < RA_BPB; j += 8) {
    size_t base = (size_t)(b * RA_BPB + j) * C + l * 4;
    float4 vs = *(const float4*)(psum + base);
    float4 vm = *(const float4*)(pmax + base);
    s.x += vs.x; s.y += vs.y; s.z += vs.z; s.w += vs.w;
    m.x = fmaxf(m.x, vm.x); m.y = fmaxf(m.y, vm.y);
    m.z = fmaxf(m.z, vm.z); m.w = fmaxf(m.w, vm.w);
  }
  __shared__ float ssum[8][C], smax[8][C];
  *(float4*)&ssum[g][l * 4] = s;
  *(float4*)&smax[g][l * 4] = m;
  __syncthreads();
  __shared__ float avgs[C], mxs[C];
  if (threadIdx.x < C) {
    int c = threadIdx.x;
    float S = 0.f, M = -INFINITY;
#pragma unroll
    for (int gg = 0; gg < 8; ++gg) {
      S += ssum[gg][c];
      M = fmaxf(M, smax[gg][c]);
    }
    avgs[c] = S / (float)NPER;
    mxs[c] = M;
  }
  __syncthreads();
  __shared__ float h1a[64], h1m[64];
  int t = threadIdx.x;
  if (t < 64) {
    float sa = b1[t], sm = b1[t];
    for (int c = 0; c < C; ++c) {
      float wv = w1[c * 64 + t];
      sa += avgs[c] * wv;
      sm += mxs[c] * wv;
    }
    h1a[t] = fmaxf(sa, 0.f);
    h1m[t] = fmaxf(sm, 0.f);
  }
  __syncthreads();
  if (t < C) {
    float za = b2[t], zm = b2[t];
    for (int h = 0; h < 64; ++h) {
      float wv = w2[h * C + t];
      za += h1a[h] * wv;
      zm += h1m[h] * wv;
    }
    float z = za + zm;
    wgt[b * C + t] = 1.f / (1.f + expf(-z));
  }
}

// ---------------------------------------------------------------- sparse 3x3x3 conv C->4 + BN partials
// One ROW-PAIR per ballot (2x27=54 mask bits in one 64-bit ballot); one mask
// load + one idx load + one ballot per 2 rows. Depth-2 pipeline over pairs.
// Per-row reduction: select-then-exchange (2x shfl32 + 1x shfl16 + 6 cndmask)
// replaces 8 shfl; then xor 1,2,4,8 on one value. DS ops/row: 10 -> 5.
__global__ __launch_bounds__(CONV_TPB, 8) void conv_kernel(
    const float* __restrict__ feats, const float* __restrict__ wgt,
    const float* __restrict__ conv1_w, const int* __restrict__ nbr_idx,
    const void* __restrict__ nbr_mask, const int* __restrict__ flagp,
    float* __restrict__ y, float* __restrict__ bnpart, int N, int NPER) {
  __shared__ __align__(16) h8 wlds[K * 64];  // 27648 B
  int tid = threadIdx.x;
  for (int e = tid; e < K * 64; e += CONV_TPB) {
    float4 A = ((const float4*)conv1_w)[e * 2];
    float4 B = ((const float4*)conv1_w)[e * 2 + 1];
    h8 w;
    h2 p;
    p = __builtin_amdgcn_cvt_pkrtz(A.x, B.x); w[0] = p[0]; w[1] = p[1];
    p = __builtin_amdgcn_cvt_pkrtz(A.y, B.y); w[2] = p[0]; w[3] = p[1];
    p = __builtin_amdgcn_cvt_pkrtz(A.z, B.z); w[4] = p[0]; w[5] = p[1];
    p = __builtin_amdgcn_cvt_pkrtz(A.w, B.w); w[6] = p[0]; w[7] = p[1];
    wlds[e] = w;
  }
  __syncthreads();

  int lane = tid & 63;
  int g = lane >> 4, cl = lane & 15;
  int gwave = blockIdx.x * (CONV_TPB / 64) + (tid >> 6);
  int nwaves = gridDim.x * (CONV_TPB / 64);
  int Q = (N + 1) >> 1;  // row pairs
  int qpw = (Q + nwaves - 1) / nwaves;
  int qbeg = gwave * qpw, qend = min(Q, qbeg + qpw);
  bool byteMode = (*flagp != 0);
  const unsigned char* mb = (const unsigned char*)nbr_mask;
  const int* mi = (const int*)nbr_mask;
  long long maxE = (long long)N * K;

  int bB = min((2 * qbeg) / NPER, BATCHES - 1);
  int bEnd = (bB + 1) * NPER;
  float2 wr = *(const float2*)(wgt + bB * C + 2 * lane);

  // prime mask/idx for pair qbeg (rows 2q, 2q+1; lanes 0..53)
  bool mk = false;
  int jl = 0;
  if (qbeg < qend && lane < 2 * K) {
    long long e = (long long)(2 * qbeg) * K + lane;
    if (e < maxE) {
      mk = byteMode ? (mb[e] != 0) : (mi[e] != 0);
      jl = nbr_idx[e];
    }
  }

  float sAcc = 0.f, qAcc = 0.f;  // BN partials for this lane's output group g

  // pipeline banks (N = being fetched, P = ready): per bank, rows A and B
  int jN = 0, jP = 0;
  unsigned tailAN = 0, tailBN = 0, tailAP = 0, tailBP = 0;
  int cntAN = 0, cntBN = 0, cntAP = 0, cntBP = 0;
  int kA0N = 0, kA1N = 0, kA2N = 0, kA3N = 0, kB0N = 0, kB1N = 0, kB2N = 0, kB3N = 0;
  int kA0P = 0, kA1P = 0, kA2P = 0, kA3P = 0, kB0P = 0, kB1P = 0, kB2P = 0, kB3P = 0;
  float2 gA0N, gA1N, gA2N, gA3N, gB0N, gB1N, gB2N, gB3N;
  float2 gA0P, gA1P, gA2P, gA3P, gB0P, gB1P, gB2P, gB3P;
  gA0N = gA1N = gA2N = gA3N = gB0N = gB1N = gB2N = gB3N = make_float2(0.f, 0.f);
  gA0P = gA1P = gA2P = gA3P = gB0P = gB1P = gB2P = gB3P = make_float2(0.f, 0.f);

#define FRONT(qF)                                                           \
  do {                                                                      \
    unsigned long long bb = __ballot(mk);                                   \
    jN = jl;                                                                \
    mk = false;                                                             \
    if ((qF) + 1 < qend && lane < 2 * K) {                                  \
      long long e = (long long)(2 * ((qF) + 1)) * K + lane;                 \
      if (e < maxE) {                                                       \
        mk = byteMode ? (mb[e] != 0) : (mi[e] != 0);                        \
        jl = nbr_idx[e];                                                    \
      }                                                                     \
    }                                                                       \
    unsigned balA = (unsigned)(bb & 0x7FFFFFFull);                          \
    unsigned balB = (unsigned)((bb >> 27) & 0x7FFFFFFull);                  \
    cntAN = __popc(balA); cntBN = __popc(balB);                             \
    kA0N = __ffs(balA) - 1; balA &= balA - 1;                               \
    kA1N = __ffs(balA) - 1; balA &= balA - 1;                               \
    kA2N = __ffs(balA) - 1; balA &= balA - 1;                               \
    kA3N = __ffs(balA) - 1; balA &= balA - 1;                               \
    tailAN = balA;                                                          \
    kB0N = __ffs(balB) - 1; balB &= balB - 1;                               \
    kB1N = __ffs(balB) - 1; balB &= balB - 1;                               \
    kB2N = __ffs(balB) - 1; balB &= balB - 1;                               \
    kB3N = __ffs(balB) - 1; balB &= balB - 1;                               \
    tailBN = balB;                                                          \
    int jA0 = __shfl(jN, kA0N & 63);                                        \
    int jA1 = __shfl(jN, kA1N & 63);                                        \
    int jA2 = __shfl(jN, kA2N & 63);                                        \
    int jA3 = __shfl(jN, kA3N & 63);                                        \
    int jB0 = __shfl(jN, (27 + kB0N) & 63);                                 \
    int jB1 = __shfl(jN, (27 + kB1N) & 63);                                 \
    int jB2 = __shfl(jN, (27 + kB2N) & 63);                                 \
    int jB3 = __shfl(jN, (27 + kB3N) & 63);                                 \
    if (cntAN > 0) gA0N = *(const float2*)(feats + (size_t)jA0 * C + 2 * lane); \
    if (cntAN > 1) gA1N = *(const float2*)(feats + (size_t)jA1 * C + 2 * lane); \
    if (cntAN > 2) gA2N = *(const float2*)(feats + (size_t)jA2 * C + 2 * lane); \
    if (cntAN > 3) gA3N = *(const float2*)(feats + (size_t)jA3 * C + 2 * lane); \
    if (cntBN > 0) gB0N = *(const float2*)(feats + (size_t)jB0 * C + 2 * lane); \
    if (cntBN > 1) gB1N = *(const float2*)(feats + (size_t)jB1 * C + 2 * lane); \
    if (cntBN > 2) gB2N = *(const float2*)(feats + (size_t)jB2 * C + 2 * lane); \
    if (cntBN > 3) gB3N = *(const float2*)(feats + (size_t)jB3 * C + 2 * lane); \
  } while (0)

#define ACCD(ff, kk)                                                        \
  {                                                                         \
    h2 fp = __builtin_amdgcn_cvt_pkrtz(ff.x * wr.x, ff.y * wr.y);           \
    h8 w = wlds[(kk)*64 + lane];                                            \
    h2 w0 = __builtin_shufflevector(w, w, 0, 1);                            \
    h2 w1 = __builtin_shufflevector(w, w, 2, 3);                            \
    h2 w2 = __builtin_shufflevector(w, w, 4, 5);                            \
    h2 w3 = __builtin_shufflevector(w, w, 6, 7);                            \
    a0 = __builtin_amdgcn_fdot2(fp, w0, a0, false);                         \
    a1 = __builtin_amdgcn_fdot2(fp, w1, a1, false);                         \
    a2 = __builtin_amdgcn_fdot2(fp, w2, a2, false);                         \
    a3 = __builtin_amdgcn_fdot2(fp, w3, a3, false);                         \
  }

  // select-then-exchange reduction: 5 DS-class ops total per row
#define REDUCE_STORE(ir)                                                    \
  do {                                                                      \
    float u = (g < 2) ? a2 : a0;                                            \
    float vv = (g < 2) ? a3 : a1;                                           \
    float m0 = ((g < 2) ? a0 : a2) + __shfl_xor(u, 32);                     \
    float m1 = ((g < 2) ? a1 : a3) + __shfl_xor(vv, 32);                    \
    float w = (g & 1) ? m0 : m1;                                            \
    float vf = ((g & 1) ? m1 : m0) + __shfl_xor(w, 16);                     \
    vf += __shfl_xor(vf, 1);                                                \
    vf += __shfl_xor(vf, 2);                                                \
    vf += __shfl_xor(vf, 4);                                                \
    vf += __shfl_xor(vf, 8);                                                \
    if (cl == 0) y[(size_t)(ir)*4 + g] = vf;                                \
    sAcc += vf; qAcc += vf * vf;                                            \
  } while (0)

#define BACKROW(cnt, K0, K1, K2, K3, TAIL, G0, G1, G2, G3, SOFF, ir)        \
  do {                                                                      \
    float a0 = 0, a1 = 0, a2 = 0, a3 = 0;                                   \
    if (cnt > 0) ACCD(G0, K0)                                               \
    if (cnt > 1) ACCD(G1, K1)                                               \
    if (cnt > 2) ACCD(G2, K2)                                               \
    if (cnt > 3) ACCD(G3, K3)                                               \
    unsigned bt = TAIL;                                                     \
    while (bt) {                                                            \
      int kk = __ffs(bt) - 1; bt &= bt - 1;                                 \
      int jj = __shfl(jP, (SOFF) + kk);                                     \
      float2 f = *(const float2*)(feats + (size_t)jj * C + 2 * lane);       \
      ACCD(f, kk)                                                           \
    }                                                                       \
    REDUCE_STORE(ir);                                                       \
  } while (0)

#define BACKPAIR(qr)                                                        \
  do {                                                                      \
    int rA = 2 * (qr);                                                      \
    if (rA >= bEnd && bB < BATCHES - 1) {                                   \
      ++bB; bEnd += NPER;                                                   \
      wr = *(const float2*)(wgt + bB * C + 2 * lane);                       \
    }                                                                       \
    BACKROW(cntAP, kA0P, kA1P, kA2P, kA3P, tailAP, gA0P, gA1P, gA2P, gA3P, 0, rA); \
    if (rA + 1 < N)                                                         \
      BACKROW(cntBP, kB0P, kB1P, kB2P, kB3P, tailBP, gB0P, gB1P, gB2P, gB3P, 27, rA + 1); \
  } while (0)

#define ROTATE()                                                            \
  do {                                                                      \
    jP = jN;                                                                \
    tailAP = tailAN; tailBP = tailBN;                                       \
    cntAP = cntAN; cntBP = cntBN;                                           \
    kA0P = kA0N; kA1P = kA1N; kA2P = kA2N; kA3P = kA3N;                     \
    kB0P = kB0N; kB1P = kB1N; kB2P = kB2N; kB3P = kB3N;                     \
    gA0P = gA0N; gA1P = gA1N; gA2P = gA2N; gA3P = gA3N;                     \
    gB0P = gB0N; gB1P = gB1N; gB2P = gB2N; gB3P = gB3N;                     \
  } while (0)

  if (qbeg < qend) {
    FRONT(qbeg);
    ROTATE();
    for (int q = qbeg + 1; q < qend; ++q) {
      FRONT(q);      // issue pair q's gathers (hidden under BACKPAIR(q-1))
      BACKPAIR(q - 1);
      ROTATE();
    }
    BACKPAIR(qend - 1);
  }
#undef FRONT
#undef ACCD
#undef REDUCE_STORE
#undef BACKROW
#undef BACKPAIR
#undef ROTATE

  if (cl == 0) {
    float* p = bnpart + (size_t)gwave * 8;
    p[g] = sAcc;
    p[4 + g] = qAcc;
  }
}

// ---------------------------------------------------------------- BN stat reduce -> scale/shift
__global__ void bn_reduce_kernel(const float* __restrict__ bnpart, int nparts,
                                 const float* __restrict__ gamma, const float* __restrict__ beta,
                                 float* __restrict__ scsh, int N) {
  __shared__ float red[256 * 8];
  int t = threadIdx.x;
  float S[8];
#pragma unroll
  for (int o = 0; o < 8; ++o) S[o] = 0.f;
  for (int i = t; i < nparts; i += 256) {
#pragma unroll
    for (int o = 0; o < 8; ++o) S[o] += bnpart[(size_t)i * 8 + o];
  }
#pragma unroll
  for (int o = 0; o < 8; ++o) red[t * 8 + o] = S[o];
  __syncthreads();
  for (int st = 128; st > 0; st >>= 1) {
    if (t < st) {
#pragma unroll
      for (int o = 0; o < 8; ++o) red[t * 8 + o] += red[(t + st) * 8 + o];
    }
    __syncthreads();
  }
  if (t == 0) {
    float invN = 1.f / (float)N;
#pragma unroll
    for (int o = 0; o < 4; ++o) {
      float mu = red[o] * invN;
      float var = red[4 + o] * invN - mu * mu;
      float sc = gamma[o] * rsqrtf(var + BN_EPS);
      scsh[o] = sc;
      scsh[4 + o] = beta[o] - mu * sc;
    }
  }
}

// ---------------------------------------------------------------- fused epilogue
__global__ __launch_bounds__(256) void final_kernel(
    const float* __restrict__ feats, const float* __restrict__ wgt,
    const float* __restrict__ y, const float* __restrict__ scsh,
    const float* __restrict__ c2, float* __restrict__ out, int N, int NPER) {
  int lane = threadIdx.x & 63;
  int gwave = blockIdx.x * (blockDim.x >> 6) + (threadIdx.x >> 6);
  int nwaves = gridDim.x * (blockDim.x >> 6);
  int rpw = (N + nwaves - 1) / nwaves;
  int rbeg = gwave * rpw, rend = min(N, rbeg + rpw);
  if (rbeg >= rend) return;
  float4 sc = *(const float4*)scsh;
  float4 sh = *(const float4*)(scsh + 4);
  float4 r0 = *(const float4*)(c2 + 0);
  float4 r1 = *(const float4*)(c2 + 4);
  float4 r2 = *(const float4*)(c2 + 8);
  float4 r3 = *(const float4*)(c2 + 12);
  int bB = min(rbeg / NPER, BATCHES - 1);
  int bEnd = (bB + 1) * NPER;
  float2 w = *(const float2*)(wgt + bB * C + 2 * lane);

  float4 yvN = *(const float4*)(y + (size_t)rbeg * 4);
  float2 fN = *(const float2*)(feats + (size_t)rbeg * C + 2 * lane);
  for (int i = rbeg; i < rend; ++i) {
    float4 yv = yvN;
    float2 f = fN;
    if (i + 1 < rend) {
      yvN = *(const float4*)(y + (size_t)(i + 1) * 4);
      fN = *(const float2*)(feats + (size_t)(i + 1) * C + 2 * lane);
    }
    if (i >= bEnd && bB < BATCHES - 1) {
      ++bB; bEnd += NPER;
      w = *(const float2*)(wgt + bB * C + 2 * lane);
    }
    float y0 = fmaxf(yv.x * sc.x + sh.x, 0.f);
    float y1 = fmaxf(yv.y * sc.y + sh.y, 0.f);
    float y2 = fmaxf(yv.z * sc.z + sh.z, 0.f);
    float y3 = fmaxf(yv.w * sc.w + sh.w, 0.f);
    float z0 = y0 * r0.x + y1 * r1.x + y2 * r2.x + y3 * r3.x;
    float z1 = y0 * r0.y + y1 * r1.y + y2 * r2.y + y3 * r3.y;
    float z2 = y0 * r0.z + y1 * r1.z + y2 * r2.z + y3 * r3.z;
    float z3 = y0 * r0.w + y1 * r1.w + y2 * r2.w + y3 * r3.w;
    float zm = fmaxf(fmaxf(z0, z1), fmaxf(z2, z3));
    float gate = 1.f / (1.f + expf(-zm));
    float g1 = 1.f + gate;
    float2 o2;
    o2.x = f.x * (1.f + w.x * g1);
    o2.y = f.y * (1.f + w.y * g1);
    *(float2*)(out + (size_t)i * C + 2 * lane) = o2;
  }
}

extern "C" void kernel_launch(void* const* d_in, const int* in_sizes, int n_in,
                              void* d_out, int out_size, void* d_ws, size_t ws_size,
                              hipStream_t stream) {
  const float* feats   = (const float*)d_in[0];
  const float* w1      = (const float*)d_in[1];
  const float* b1      = (const float*)d_in[2];
  const float* w2      = (const float*)d_in[3];
  const float* b2      = (const float*)d_in[4];
  const float* conv1w  = (const float*)d_in[5];
  const float* gamma   = (const float*)d_in[6];
  const float* beta    = (const float*)d_in[7];
  const float* c2      = (const float*)d_in[8];
  const int*   nbr_idx = (const int*)d_in[9];
  const void*  nbr_mask = d_in[10];
  int N = in_sizes[0] / C;
  int NPER = N / BATCHES;

  char* ws = (char*)d_ws;
  size_t off = 0;
  int* flag = (int*)(ws + off);        off += 16;
  float* psum = (float*)(ws + off);    off += (size_t)BATCHES * RA_BPB * C * 4;
  float* pmax = (float*)(ws + off);    off += (size_t)BATCHES * RA_BPB * C * 4;
  float* wgt  = (float*)(ws + off);    off += (size_t)BATCHES * C * 4;
  float* y    = (float*)(ws + off);    off += (size_t)N * 4 * 4;
  float* bnpart = (float*)(ws + off);  off += (size_t)NWAVES_CONV * 8 * 4;
  float* scsh = (float*)(ws + off);    off += 64;
  float* outp = (float*)d_out;

  hipMemsetAsync(flag, 0, sizeof(int), stream);
  reduceA_kernel<<<BATCHES * RA_BPB, 256, 0, stream>>>(
      feats, psum, pmax, (const unsigned int*)nbr_mask, flag, NPER);
  reduceB_mlp_kernel<<<BATCHES, 256, 0, stream>>>(psum, pmax, w1, b1, w2, b2, wgt, NPER);
  conv_kernel<<<CONV_BLOCKS, CONV_TPB, 0, stream>>>(feats, wgt, conv1w, nbr_idx, nbr_mask,
                                                    flag, y, bnpart, N, NPER);
  bn_reduce_kernel<<<1, 256, 0, stream>>>(bnpart, NWAVES_CONV, gamma, beta, scsh, N);
  final_kernel<<<2048, 256, 0, stream>>>(feats, wgt, y, scsh, c2, outp, N, NPER);
}

// Round 12
// 158.317 us; speedup vs baseline: 1.2284x; 1.2284x over previous
//
#include <hip/hip_runtime.h>

#define C 128
#define K 27
#define BATCHES 4
#define RA_BPB 512            // stage-A blocks per batch
#define CONV_BLOCKS 512
#define CONV_TPB 1024
#define NWAVES_CONV (CONV_BLOCKS * (CONV_TPB / 64))   // 8192
#define BN_EPS 1e-5f

typedef __attribute__((ext_vector_type(2))) __fp16 h2;
typedef __attribute__((ext_vector_type(8))) __fp16 h8;

// ---------------------------------------------------------------- stage A reduce + mask dtype probe
__global__ __launch_bounds__(256) void reduceA_kernel(
    const float* __restrict__ feats, float* __restrict__ psum,
    float* __restrict__ pmax, const unsigned int* __restrict__ mwords,
    int* __restrict__ flag, int NPER) {
  int base = blockIdx.x * 512;
  bool bad = false;
  bad |= (mwords[base + threadIdx.x] > 1u);
  bad |= (mwords[base + 256 + threadIdx.x] > 1u);
  if (__any(bad) && (threadIdx.x & 63) == 0) atomicOr(flag, 1);

  int b = blockIdx.x / RA_BPB, chunk = blockIdx.x % RA_BPB;
  int CH = (NPER + RA_BPB - 1) / RA_BPB;
  int r0 = b * NPER + chunk * CH;
  int r1 = min(b * NPER + NPER, r0 + CH);
  int g = threadIdx.x >> 5;   // 8 row groups
  int l = threadIdx.x & 31;   // lane -> channels 4l..4l+3
  float4 s = make_float4(0.f, 0.f, 0.f, 0.f);
  float4 m = make_float4(-INFINITY, -INFINITY, -INFINITY, -INFINITY);
  int i = r0 + g;
  for (; i + 8 < r1; i += 16) {
    float4 v1 = *(const float4*)(feats + (size_t)i * C + l * 4);
    float4 v2 = *(const float4*)(feats + (size_t)(i + 8) * C + l * 4);
    s.x += v1.x + v2.x; s.y += v1.y + v2.y;
    s.z += v1.z + v2.z; s.w += v1.w + v2.w;
    m.x = fmaxf(m.x, fmaxf(v1.x, v2.x)); m.y = fmaxf(m.y, fmaxf(v1.y, v2.y));
    m.z = fmaxf(m.z, fmaxf(v1.z, v2.z)); m.w = fmaxf(m.w, fmaxf(v1.w, v2.w));
  }
  if (i < r1) {
    float4 v = *(const float4*)(feats + (size_t)i * C + l * 4);
    s.x += v.x; s.y += v.y; s.z += v.z; s.w += v.w;
    m.x = fmaxf(m.x, v.x); m.y = fmaxf(m.y, v.y);
    m.z = fmaxf(m.z, v.z); m.w = fmaxf(m.w, v.w);
  }
  __shared__ float ssum[8][C], smax[8][C];
  *(float4*)&ssum[g][l * 4] = s;
  *(float4*)&smax[g][l * 4] = m;
  __syncthreads();
  if (threadIdx.x < C) {
    int c = threadIdx.x;
    float S = 0.f, M = -INFINITY;
#pragma unroll
    for (int gg = 0; gg < 8; ++gg) {
      S += ssum[gg][c];
      M = fmaxf(M, smax[gg][c]);
    }
    psum[(size_t)blockIdx.x * C + c] = S;
    pmax[(size_t)blockIdx.x * C + c] = M;
  }
}

// ---------------------------------------------------------------- stage B + channel MLP (fused)
__global__ __launch_bounds__(256) void reduceB_mlp_kernel(
    const float* __restrict__ psum, const float* __restrict__ pmax,
    const float* __restrict__ w1, const float* __restrict__ b1,
    const float* __restrict__ w2, const float* __restrict__ b2,
    float* __restrict__ wgt, int NPER) {
  int b = blockIdx.x;
  int g = threadIdx.x >> 5, l = threadIdx.x & 31;
  float4 s = make_float4(0.f, 0.f, 0.f, 0.f);
  float4 m = make_float4(-INFINITY, -INFINITY, -INFINITY, -INFINITY);
  for (int j = g; j < RA_BPB; j += 8) {
    size_t base = (size_t)(b * RA_BPB + j) * C + l * 4;
    float4 vs = *(const float4*)(psum + base);
    float4 vm = *(const float4*)(pmax + base);
    s.x += vs.x; s.y += vs.y; s.z += vs.z; s.w += vs.w;
    m.x = fmaxf(m.x, vm.x); m.y = fmaxf(m.y, vm.y);
    m.z = fmaxf(m.z, vm.z); m.w = fmaxf(m.w, vm.w);
  }
  __shared__ float ssum[8][C], smax[8][C];
  *(float4*)&ssum[g][l * 4] = s;
  *(float4*)&smax[g][l * 4] = m;
  __syncthreads();
  __shared__ float avgs[C], mxs[C];
  if (threadIdx.x < C) {
    int c = threadIdx.x;
    float S = 0.f, M = -INFINITY;
#pragma unroll
    for (int gg = 0; gg < 8; ++gg) {
      S += ssum[gg][c];
      M = fmaxf(M, smax[gg][c]);
    }
    avgs[c] = S / (float)NPER;
    mxs[c] = M;
  }
  __syncthreads();
  __shared__ float h1a[64], h1m[64];
  int t = threadIdx.x;
  if (t < 64) {
    float sa = b1[t], sm = b1[t];
    for (int c = 0; c < C; ++c) {
      float wv = w1[c * 64 + t];
      sa += avgs[c] * wv;
      sm += mxs[c] * wv;
    }
    h1a[t] = fmaxf(sa, 0.f);
    h1m[t] = fmaxf(sm, 0.f);
  }
  __syncthreads();
  if (t < C) {
    float za = b2[t], zm = b2[t];
    for (int h = 0; h < 64; ++h) {
      float wv = w2[h * C + t];
      za += h1a[h] * wv;
      zm += h1m[h] * wv;
    }
    float z = za + zm;
    wgt[b * C + t] = 1.f / (1.f + expf(-z));
  }
}

// ---------------------------------------------------------------- sparse 3x3x3 conv C->4 + BN partials
// One row per wave, 2 channels/lane, single-row ballot, depth-2 pipeline
// (R9/R11 measured: >2 rows in flight inflates HBM FETCH 35-50% -> never).
// Weights in LDS as f16 channel-pairs (1 conflict-free ds_read_b128/nbr);
// 2 mul + cvt_pkrtz + 4 fdot2 per neighbor. Reduction: select-then-exchange
// (xor32 + xor16 with cndmask) + xor 1/2/4/8 -> 6 DS ops/row (was 12).
__global__ __launch_bounds__(CONV_TPB, 8) void conv_kernel(
    const float* __restrict__ feats, const float* __restrict__ wgt,
    const float* __restrict__ conv1_w, const int* __restrict__ nbr_idx,
    const void* __restrict__ nbr_mask, const int* __restrict__ flagp,
    float* __restrict__ y, float* __restrict__ bnpart, int N, int NPER) {
  __shared__ __align__(16) h8 wlds[K * 64];  // 27648 B
  int tid = threadIdx.x;
  for (int e = tid; e < K * 64; e += CONV_TPB) {
    float4 A = ((const float4*)conv1_w)[e * 2];
    float4 B = ((const float4*)conv1_w)[e * 2 + 1];
    h8 w;
    h2 p;
    p = __builtin_amdgcn_cvt_pkrtz(A.x, B.x); w[0] = p[0]; w[1] = p[1];
    p = __builtin_amdgcn_cvt_pkrtz(A.y, B.y); w[2] = p[0]; w[3] = p[1];
    p = __builtin_amdgcn_cvt_pkrtz(A.z, B.z); w[4] = p[0]; w[5] = p[1];
    p = __builtin_amdgcn_cvt_pkrtz(A.w, B.w); w[6] = p[0]; w[7] = p[1];
    wlds[e] = w;
  }
  __syncthreads();

  int lane = tid & 63;
  int g = lane >> 4, cl = lane & 15;
  int gwave = blockIdx.x * (CONV_TPB / 64) + (tid >> 6);
  int nwaves = gridDim.x * (CONV_TPB / 64);
  int rpw = (N + nwaves - 1) / nwaves;
  int rbeg = gwave * rpw, rend = min(N, rbeg + rpw);
  bool byteMode = (*flagp != 0);
  const unsigned char* mb = (const unsigned char*)nbr_mask;
  const int* mi = (const int*)nbr_mask;

  int bB = min(rbeg / NPER, BATCHES - 1);
  int bEnd = (bB + 1) * NPER;
  float2 wr = *(const float2*)(wgt + bB * C + 2 * lane);

  // prime mask/idx for row rbeg
  bool mk = false;
  int jl = 0;
  if (rbeg < rend && lane < K) {
    size_t e = (size_t)rbeg * K + lane;
    mk = byteMode ? (mb[e] != 0) : (mi[e] != 0);
    jl = nbr_idx[e];
  }

  float sAcc = 0.f, qAcc = 0.f;  // BN partials for this lane's output group g

  // pipeline registers (N = being fetched, P = ready for compute)
  unsigned balTailN = 0, balTailP = 0;
  int jN = 0, jP = 0, cntN = 0, cntP = 0;
  int k0N = 0, k1N = 0, k2N = 0, k3N = 0, k0P = 0, k1P = 0, k2P = 0, k3P = 0;
  float2 g0N = make_float2(0, 0), g1N = g0N, g2N = g0N, g3N = g0N;
  float2 g0P = g0N, g1P = g0N, g2P = g0N, g3P = g0N;

#define FRONT(iF)                                                           \
  do {                                                                      \
    unsigned bb = (unsigned)__ballot(mk);                                   \
    jN = jl;                                                                \
    mk = false;                                                             \
    if ((iF) + 1 < rend && lane < K) {                                      \
      size_t e = (size_t)((iF) + 1) * K + lane;                             \
      mk = byteMode ? (mb[e] != 0) : (mi[e] != 0);                          \
      jl = nbr_idx[e];                                                      \
    }                                                                       \
    cntN = __popc(bb);                                                      \
    k0N = __ffs(bb) - 1; bb &= bb - 1;                                      \
    k1N = __ffs(bb) - 1; bb &= bb - 1;                                      \
    k2N = __ffs(bb) - 1; bb &= bb - 1;                                      \
    k3N = __ffs(bb) - 1; bb &= bb - 1;                                      \
    balTailN = bb;                                                          \
    int j0 = __shfl(jN, k0N & 63);                                          \
    int j1 = __shfl(jN, k1N & 63);                                          \
    int j2 = __shfl(jN, k2N & 63);                                          \
    int j3 = __shfl(jN, k3N & 63);                                          \
    if (cntN > 0) g0N = *(const float2*)(feats + (size_t)j0 * C + 2 * lane);\
    if (cntN > 1) g1N = *(const float2*)(feats + (size_t)j1 * C + 2 * lane);\
    if (cntN > 2) g2N = *(const float2*)(feats + (size_t)j2 * C + 2 * lane);\
    if (cntN > 3) g3N = *(const float2*)(feats + (size_t)j3 * C + 2 * lane);\
  } while (0)

#define ACCD(ff, kk)                                                        \
  {                                                                         \
    h2 fp = __builtin_amdgcn_cvt_pkrtz(ff.x * wr.x, ff.y * wr.y);           \
    h8 w = wlds[(kk)*64 + lane];                                            \
    h2 w0 = __builtin_shufflevector(w, w, 0, 1);                            \
    h2 w1 = __builtin_shufflevector(w, w, 2, 3);                            \
    h2 w2 = __builtin_shufflevector(w, w, 4, 5);                            \
    h2 w3 = __builtin_shufflevector(w, w, 6, 7);                            \
    a0 = __builtin_amdgcn_fdot2(fp, w0, a0, false);                         \
    a1 = __builtin_amdgcn_fdot2(fp, w1, a1, false);                         \
    a2 = __builtin_amdgcn_fdot2(fp, w2, a2, false);                         \
    a3 = __builtin_amdgcn_fdot2(fp, w3, a3, false);                         \
  }

#define BACK(ir)                                                            \
  do {                                                                      \
    if ((ir) >= bEnd && bB < BATCHES - 1) {                                 \
      ++bB; bEnd += NPER;                                                   \
      wr = *(const float2*)(wgt + bB * C + 2 * lane);                       \
    }                                                                       \
    float a0 = 0, a1 = 0, a2 = 0, a3 = 0;                                   \
    if (cntP > 0) ACCD(g0P, k0P)                                            \
    if (cntP > 1) ACCD(g1P, k1P)                                            \
    if (cntP > 2) ACCD(g2P, k2P)                                            \
    if (cntP > 3) ACCD(g3P, k3P)                                            \
    unsigned bt = balTailP;                                                 \
    while (bt) {                                                            \
      int kk = __ffs(bt) - 1; bt &= bt - 1;                                 \
      int jj = __shfl(jP, kk);                                              \
      float2 f = *(const float2*)(feats + (size_t)jj * C + 2 * lane);       \
      ACCD(f, kk)                                                           \
    }                                                                       \
    float u = (g < 2) ? a2 : a0;                                            \
    float vv = (g < 2) ? a3 : a1;                                           \
    float m0 = ((g < 2) ? a0 : a2) + __shfl_xor(u, 32);                     \
    float m1 = ((g < 2) ? a1 : a3) + __shfl_xor(vv, 32);                    \
    float w = (g & 1) ? m0 : m1;                                            \
    float vf = ((g & 1) ? m1 : m0) + __shfl_xor(w, 16);                     \
    vf += __shfl_xor(vf, 1);                                                \
    vf += __shfl_xor(vf, 2);                                                \
    vf += __shfl_xor(vf, 4);                                                \
    vf += __shfl_xor(vf, 8);                                                \
    if (cl == 0) y[(size_t)(ir)*4 + g] = vf;                                \
    sAcc += vf; qAcc += vf * vf;                                            \
  } while (0)

#define ROTATE()                                                            \
  do {                                                                      \
    balTailP = balTailN; jP = jN; cntP = cntN;                              \
    k0P = k0N; k1P = k1N; k2P = k2N; k3P = k3N;                             \
    g0P = g0N; g1P = g1N; g2P = g2N; g3P = g3N;                             \
  } while (0)

  if (rbeg < rend) {
    FRONT(rbeg);
    ROTATE();
    for (int i = rbeg + 1; i < rend; ++i) {
      FRONT(i);     // issue row i's gathers (latency hidden under BACK(i-1))
      BACK(i - 1);
      ROTATE();
    }
    BACK(rend - 1);
  }
#undef FRONT
#undef ACCD
#undef BACK
#undef ROTATE

  // sAcc/qAcc identical across the 16 lanes of each group; cl==0 writes
  if (cl == 0) {
    float* p = bnpart + (size_t)gwave * 8;
    p[g] = sAcc;
    p[4 + g] = qAcc;
  }
}

// ---------------------------------------------------------------- BN stat reduce -> scale/shift
__global__ void bn_reduce_kernel(const float* __restrict__ bnpart, int nparts,
                                 const float* __restrict__ gamma, const float* __restrict__ beta,
                                 float* __restrict__ scsh, int N) {
  __shared__ float red[256 * 8];
  int t = threadIdx.x;
  float S[8];
#pragma unroll
  for (int o = 0; o < 8; ++o) S[o] = 0.f;
  for (int i = t; i < nparts; i += 256) {
#pragma unroll
    for (int o = 0; o < 8; ++o) S[o] += bnpart[(size_t)i * 8 + o];
  }
#pragma unroll
  for (int o = 0; o < 8; ++o) red[t * 8 + o] = S[o];
  __syncthreads();
  for (int st = 128; st > 0; st >>= 1) {
    if (t < st) {
#pragma unroll
      for (int o = 0; o < 8; ++o) red[t * 8 + o] += red[(t + st) * 8 + o];
    }
    __syncthreads();
  }
  if (t == 0) {
    float invN = 1.f / (float)N;
#pragma unroll
    for (int o = 0; o < 4; ++o) {
      float mu = red[o] * invN;
      float var = red[4 + o] * invN - mu * mu;
      float sc = gamma[o] * rsqrtf(var + BN_EPS);
      scsh[o] = sc;
      scsh[4 + o] = beta[o] - mu * sc;
    }
  }
}

// ---------------------------------------------------------------- fused epilogue
__global__ __launch_bounds__(256) void final_kernel(
    const float* __restrict__ feats, const float* __restrict__ wgt,
    const float* __restrict__ y, const float* __restrict__ scsh,
    const float* __restrict__ c2, float* __restrict__ out, int N, int NPER) {
  int lane = threadIdx.x & 63;
  int gwave = blockIdx.x * (blockDim.x >> 6) + (threadIdx.x >> 6);
  int nwaves = gridDim.x * (blockDim.x >> 6);
  int rpw = (N + nwaves - 1) / nwaves;
  int rbeg = gwave * rpw, rend = min(N, rbeg + rpw);
  if (rbeg >= rend) return;
  float4 sc = *(const float4*)scsh;
  float4 sh = *(const float4*)(scsh + 4);
  float4 r0 = *(const float4*)(c2 + 0);
  float4 r1 = *(const float4*)(c2 + 4);
  float4 r2 = *(const float4*)(c2 + 8);
  float4 r3 = *(const float4*)(c2 + 12);
  int bB = min(rbeg / NPER, BATCHES - 1);
  int bEnd = (bB + 1) * NPER;
  float2 w = *(const float2*)(wgt + bB * C + 2 * lane);

  float4 yvN = *(const float4*)(y + (size_t)rbeg * 4);
  float2 fN = *(const float2*)(feats + (size_t)rbeg * C + 2 * lane);
  for (int i = rbeg; i < rend; ++i) {
    float4 yv = yvN;
    float2 f = fN;
    if (i + 1 < rend) {
      yvN = *(const float4*)(y + (size_t)(i + 1) * 4);
      fN = *(const float2*)(feats + (size_t)(i + 1) * C + 2 * lane);
    }
    if (i >= bEnd && bB < BATCHES - 1) {
      ++bB; bEnd += NPER;
      w = *(const float2*)(wgt + bB * C + 2 * lane);
    }
    float y0 = fmaxf(yv.x * sc.x + sh.x, 0.f);
    float y1 = fmaxf(yv.y * sc.y + sh.y, 0.f);
    float y2 = fmaxf(yv.z * sc.z + sh.z, 0.f);
    float y3 = fmaxf(yv.w * sc.w + sh.w, 0.f);
    float z0 = y0 * r0.x + y1 * r1.x + y2 * r2.x + y3 * r3.x;
    float z1 = y0 * r0.y + y1 * r1.y + y2 * r2.y + y3 * r3.y;
    float z2 = y0 * r0.z + y1 * r1.z + y2 * r2.z + y3 * r3.z;
    float z3 = y0 * r0.w + y1 * r1.w + y2 * r2.w + y3 * r3.w;
    float zm = fmaxf(fmaxf(z0, z1), fmaxf(z2, z3));
    float gate = 1.f / (1.f + expf(-zm));
    float g1 = 1.f + gate;
    float2 o2;
    o2.x = f.x * (1.f + w.x * g1);
    o2.y = f.y * (1.f + w.y * g1);
    *(float2*)(out + (size_t)i * C + 2 * lane) = o2;
  }
}

extern "C" void kernel_launch(void* const* d_in, const int* in_sizes, int n_in,
                              void* d_out, int out_size, void* d_ws, size_t ws_size,
                              hipStream_t stream) {
  const float* feats   = (const float*)d_in[0];
  const float* w1      = (const float*)d_in[1];
  const float* b1      = (const float*)d_in[2];
  const float* w2      = (const float*)d_in[3];
  const float* b2      = (const float*)d_in[4];
  const float* conv1w  = (const float*)d_in[5];
  const float* gamma   = (const float*)d_in[6];
  const float* beta    = (const float*)d_in[7];
  const float* c2      = (const float*)d_in[8];
  const int*   nbr_idx = (const int*)d_in[9];
  const void*  nbr_mask = d_in[10];
  int N = in_sizes[0] / C;
  int NPER = N / BATCHES;

  char* ws = (char*)d_ws;
  size_t off = 0;
  int* flag = (int*)(ws + off);        off += 16;
  float* psum = (float*)(ws + off);    off += (size_t)BATCHES * RA_BPB * C * 4;
  float* pmax = (float*)(ws + off);    off += (size_t)BATCHES * RA_BPB * C * 4;
  float* wgt  = (float*)(ws + off);    off += (size_t)BATCHES * C * 4;
  float* y    = (float*)(ws + off);    off += (size_t)N * 4 * 4;
  float* bnpart = (float*)(ws + off);  off += (size_t)NWAVES_CONV * 8 * 4;
  float* scsh = (float*)(ws + off);    off += 64;
  float* outp = (float*)d_out;

  hipMemsetAsync(flag, 0, sizeof(int), stream);
  reduceA_kernel<<<BATCHES * RA_BPB, 256, 0, stream>>>(
      feats, psum, pmax, (const unsigned int*)nbr_mask, flag, NPER);
  reduceB_mlp_kernel<<<BATCHES, 256, 0, stream>>>(psum, pmax, w1, b1, w2, b2, wgt, NPER);
  conv_kernel<<<CONV_BLOCKS, CONV_TPB, 0, stream>>>(feats, wgt, conv1w, nbr_idx, nbr_mask,
                                                    flag, y, bnpart, N, NPER);
  bn_reduce_kernel<<<1, 256, 0, stream>>>(bnpart, NWAVES_CONV, gamma, beta, scsh, N);
  final_kernel<<<2048, 256, 0, stream>>>(feats, wgt, y, scsh, c2, outp, N, NPER);
}

// Round 13
// 153.346 us; speedup vs baseline: 1.2683x; 1.0324x over previous
//
#include <hip/hip_runtime.h>

#define C 128
#define K 27
#define BATCHES 4
#define RA_BPB 512            // stage-A blocks per batch
#define CONV_BLOCKS 512       // 128 blocks per batch (batch-aligned mapping)
#define CONV_BPB (CONV_BLOCKS / BATCHES)
#define CONV_TPB 1024
#define NWAVES_CONV (CONV_BLOCKS * (CONV_TPB / 64))   // 8192
#define BN_EPS 1e-5f

typedef __attribute__((ext_vector_type(2))) __fp16 h2;
typedef __attribute__((ext_vector_type(8))) __fp16 h8;

// ---------------------------------------------------------------- stage A reduce + mask dtype probe
__global__ __launch_bounds__(256) void reduceA_kernel(
    const float* __restrict__ feats, float* __restrict__ psum,
    float* __restrict__ pmax, const unsigned int* __restrict__ mwords,
    int* __restrict__ flag, int NPER) {
  int base = blockIdx.x * 512;
  bool bad = false;
  bad |= (mwords[base + threadIdx.x] > 1u);
  bad |= (mwords[base + 256 + threadIdx.x] > 1u);
  if (__any(bad) && (threadIdx.x & 63) == 0) atomicOr(flag, 1);

  int b = blockIdx.x / RA_BPB, chunk = blockIdx.x % RA_BPB;
  int CH = (NPER + RA_BPB - 1) / RA_BPB;
  int r0 = b * NPER + chunk * CH;
  int r1 = min(b * NPER + NPER, r0 + CH);
  int g = threadIdx.x >> 5;   // 8 row groups
  int l = threadIdx.x & 31;   // lane -> channels 4l..4l+3
  float4 s = make_float4(0.f, 0.f, 0.f, 0.f);
  float4 m = make_float4(-INFINITY, -INFINITY, -INFINITY, -INFINITY);
  int i = r0 + g;
  for (; i + 8 < r1; i += 16) {
    float4 v1 = *(const float4*)(feats + (size_t)i * C + l * 4);
    float4 v2 = *(const float4*)(feats + (size_t)(i + 8) * C + l * 4);
    s.x += v1.x + v2.x; s.y += v1.y + v2.y;
    s.z += v1.z + v2.z; s.w += v1.w + v2.w;
    m.x = fmaxf(m.x, fmaxf(v1.x, v2.x)); m.y = fmaxf(m.y, fmaxf(v1.y, v2.y));
    m.z = fmaxf(m.z, fmaxf(v1.z, v2.z)); m.w = fmaxf(m.w, fmaxf(v1.w, v2.w));
  }
  if (i < r1) {
    float4 v = *(const float4*)(feats + (size_t)i * C + l * 4);
    s.x += v.x; s.y += v.y; s.z += v.z; s.w += v.w;
    m.x = fmaxf(m.x, v.x); m.y = fmaxf(m.y, v.y);
    m.z = fmaxf(m.z, v.z); m.w = fmaxf(m.w, v.w);
  }
  __shared__ float ssum[8][C], smax[8][C];
  *(float4*)&ssum[g][l * 4] = s;
  *(float4*)&smax[g][l * 4] = m;
  __syncthreads();
  if (threadIdx.x < C) {
    int c = threadIdx.x;
    float S = 0.f, M = -INFINITY;
#pragma unroll
    for (int gg = 0; gg < 8; ++gg) {
      S += ssum[gg][c];
      M = fmaxf(M, smax[gg][c]);
    }
    psum[(size_t)blockIdx.x * C + c] = S;
    pmax[(size_t)blockIdx.x * C + c] = M;
  }
}

// ---------------------------------------------------------------- stage B + channel MLP (fused)
__global__ __launch_bounds__(256) void reduceB_mlp_kernel(
    const float* __restrict__ psum, const float* __restrict__ pmax,
    const float* __restrict__ w1, const float* __restrict__ b1,
    const float* __restrict__ w2, const float* __restrict__ b2,
    float* __restrict__ wgt, int NPER) {
  int b = blockIdx.x;
  int g = threadIdx.x >> 5, l = threadIdx.x & 31;
  float4 s = make_float4(0.f, 0.f, 0.f, 0.f);
  float4 m = make_float4(-INFINITY, -INFINITY, -INFINITY, -INFINITY);
  for (int j = g; j < RA_BPB; j += 8) {
    size_t base = (size_t)(b * RA_BPB + j) * C + l * 4;
    float4 vs = *(const float4*)(psum + base);
    float4 vm = *(const float4*)(pmax + base);
    s.x += vs.x; s.y += vs.y; s.z += vs.z; s.w += vs.w;
    m.x = fmaxf(m.x, vm.x); m.y = fmaxf(m.y, vm.y);
    m.z = fmaxf(m.z, vm.z); m.w = fmaxf(m.w, vm.w);
  }
  __shared__ float ssum[8][C], smax[8][C];
  *(float4*)&ssum[g][l * 4] = s;
  *(float4*)&smax[g][l * 4] = m;
  __syncthreads();
  __shared__ float avgs[C], mxs[C];
  if (threadIdx.x < C) {
    int c = threadIdx.x;
    float S = 0.f, M = -INFINITY;
#pragma unroll
    for (int gg = 0; gg < 8; ++gg) {
      S += ssum[gg][c];
      M = fmaxf(M, smax[gg][c]);
    }
    avgs[c] = S / (float)NPER;
    mxs[c] = M;
  }
  __syncthreads();
  __shared__ float h1a[64], h1m[64];
  int t = threadIdx.x;
  if (t < 64) {
    float sa = b1[t], sm = b1[t];
    for (int c = 0; c < C; ++c) {
      float wv = w1[c * 64 + t];
      sa += avgs[c] * wv;
      sm += mxs[c] * wv;
    }
    h1a[t] = fmaxf(sa, 0.f);
    h1m[t] = fmaxf(sm, 0.f);
  }
  __syncthreads();
  if (t < C) {
    float za = b2[t], zm = b2[t];
    for (int h = 0; h < 64; ++h) {
      float wv = w2[h * C + t];
      za += h1a[h] * wv;
      zm += h1m[h] * wv;
    }
    float z = za + zm;
    wgt[b * C + t] = 1.f / (1.f + expf(-z));
  }
}

// ---------------------------------------------------------------- sparse 3x3x3 conv C->4 + BN partials
// One row per wave, 2 channels/lane, single-row ballot, depth-2 pipeline
// (R9/R11 measured: >2 rows in flight inflates HBM FETCH 35-50% -> never).
// Batch-aligned block mapping (128 blocks/batch) lets each block FOLD the
// channel-attention weight wr[b][c] into its LDS f16 weights at staging:
// ACCD = 1 cvt_pkrtz + 4 fdot2 per neighbor (5 VALU, was 7), and the hot
// loop carries no batch/wr state. Reduction: select-then-exchange + xor1/2/4/8.
__global__ __launch_bounds__(CONV_TPB, 8) void conv_kernel(
    const float* __restrict__ feats, const float* __restrict__ wgt,
    const float* __restrict__ conv1_w, const int* __restrict__ nbr_idx,
    const void* __restrict__ nbr_mask, const int* __restrict__ flagp,
    float* __restrict__ y, float* __restrict__ bnpart, int N, int NPER) {
  int bat = blockIdx.x / CONV_BPB;
  const float* wgtRow = wgt + bat * C;
  __shared__ __align__(16) h8 wlds[K * 64];  // 27648 B
  int tid = threadIdx.x;
  for (int e = tid; e < K * 64; e += CONV_TPB) {
    int l = e & 63;
    float wa = wgtRow[2 * l], wb = wgtRow[2 * l + 1];
    float4 A = ((const float4*)conv1_w)[e * 2];
    float4 B = ((const float4*)conv1_w)[e * 2 + 1];
    h8 w;
    h2 p;
    p = __builtin_amdgcn_cvt_pkrtz(A.x * wa, B.x * wb); w[0] = p[0]; w[1] = p[1];
    p = __builtin_amdgcn_cvt_pkrtz(A.y * wa, B.y * wb); w[2] = p[0]; w[3] = p[1];
    p = __builtin_amdgcn_cvt_pkrtz(A.z * wa, B.z * wb); w[4] = p[0]; w[5] = p[1];
    p = __builtin_amdgcn_cvt_pkrtz(A.w * wa, B.w * wb); w[6] = p[0]; w[7] = p[1];
    wlds[e] = w;
  }
  __syncthreads();

  int lane = tid & 63;
  int g = lane >> 4, cl = lane & 15;
  int gwave = blockIdx.x * (CONV_TPB / 64) + (tid >> 6);
  int wb = (blockIdx.x % CONV_BPB) * (CONV_TPB / 64) + (tid >> 6);  // wave within batch
  int wavesPerBatch = CONV_BPB * (CONV_TPB / 64);
  int rpw = (NPER + wavesPerBatch - 1) / wavesPerBatch;
  int rbeg = bat * NPER + wb * rpw;
  int rend = min(bat * NPER + NPER, rbeg + rpw);
  bool byteMode = (*flagp != 0);
  const unsigned char* mb = (const unsigned char*)nbr_mask;
  const int* mi = (const int*)nbr_mask;

  // prime mask/idx for row rbeg
  bool mk = false;
  int jl = 0;
  if (rbeg < rend && lane < K) {
    size_t e = (size_t)rbeg * K + lane;
    mk = byteMode ? (mb[e] != 0) : (mi[e] != 0);
    jl = nbr_idx[e];
  }

  float sAcc = 0.f, qAcc = 0.f;  // BN partials for this lane's output group g

  // pipeline registers (N = being fetched, P = ready for compute)
  unsigned balTailN = 0, balTailP = 0;
  int jN = 0, jP = 0, cntN = 0, cntP = 0;
  int k0N = 0, k1N = 0, k2N = 0, k3N = 0, k0P = 0, k1P = 0, k2P = 0, k3P = 0;
  float2 g0N = make_float2(0, 0), g1N = g0N, g2N = g0N, g3N = g0N;
  float2 g0P = g0N, g1P = g0N, g2P = g0N, g3P = g0N;

#define FRONT(iF)                                                           \
  do {                                                                      \
    unsigned bb = (unsigned)__ballot(mk);                                   \
    jN = jl;                                                                \
    mk = false;                                                             \
    if ((iF) + 1 < rend && lane < K) {                                      \
      size_t e = (size_t)((iF) + 1) * K + lane;                             \
      mk = byteMode ? (mb[e] != 0) : (mi[e] != 0);                          \
      jl = nbr_idx[e];                                                      \
    }                                                                       \
    cntN = __popc(bb);                                                      \
    k0N = __ffs(bb) - 1; bb &= bb - 1;                                      \
    k1N = __ffs(bb) - 1; bb &= bb - 1;                                      \
    k2N = __ffs(bb) - 1; bb &= bb - 1;                                      \
    k3N = __ffs(bb) - 1; bb &= bb - 1;                                      \
    balTailN = bb;                                                          \
    int j0 = __shfl(jN, k0N & 63);                                          \
    int j1 = __shfl(jN, k1N & 63);                                          \
    int j2 = __shfl(jN, k2N & 63);                                          \
    int j3 = __shfl(jN, k3N & 63);                                          \
    if (cntN > 0) g0N = *(const float2*)(feats + (size_t)j0 * C + 2 * lane);\
    if (cntN > 1) g1N = *(const float2*)(feats + (size_t)j1 * C + 2 * lane);\
    if (cntN > 2) g2N = *(const float2*)(feats + (size_t)j2 * C + 2 * lane);\
    if (cntN > 3) g3N = *(const float2*)(feats + (size_t)j3 * C + 2 * lane);\
  } while (0)

#define ACCD(ff, kk)                                                        \
  {                                                                         \
    h2 fp = __builtin_amdgcn_cvt_pkrtz(ff.x, ff.y);                         \
    h8 w = wlds[(kk)*64 + lane];                                            \
    h2 w0 = __builtin_shufflevector(w, w, 0, 1);                            \
    h2 w1 = __builtin_shufflevector(w, w, 2, 3);                            \
    h2 w2 = __builtin_shufflevector(w, w, 4, 5);                            \
    h2 w3 = __builtin_shufflevector(w, w, 6, 7);                            \
    a0 = __builtin_amdgcn_fdot2(fp, w0, a0, false);                         \
    a1 = __builtin_amdgcn_fdot2(fp, w1, a1, false);                         \
    a2 = __builtin_amdgcn_fdot2(fp, w2, a2, false);                         \
    a3 = __builtin_amdgcn_fdot2(fp, w3, a3, false);                         \
  }

#define BACK(ir)                                                            \
  do {                                                                      \
    float a0 = 0, a1 = 0, a2 = 0, a3 = 0;                                   \
    if (cntP > 0) ACCD(g0P, k0P)                                            \
    if (cntP > 1) ACCD(g1P, k1P)                                            \
    if (cntP > 2) ACCD(g2P, k2P)                                            \
    if (cntP > 3) ACCD(g3P, k3P)                                            \
    unsigned bt = balTailP;                                                 \
    while (bt) {                                                            \
      int kk = __ffs(bt) - 1; bt &= bt - 1;                                 \
      int jj = __shfl(jP, kk);                                              \
      float2 f = *(const float2*)(feats + (size_t)jj * C + 2 * lane);       \
      ACCD(f, kk)                                                           \
    }                                                                       \
    float u = (g < 2) ? a2 : a0;                                            \
    float vv = (g < 2) ? a3 : a1;                                           \
    float m0 = ((g < 2) ? a0 : a2) + __shfl_xor(u, 32);                     \
    float m1 = ((g < 2) ? a1 : a3) + __shfl_xor(vv, 32);                    \
    float w = (g & 1) ? m0 : m1;                                            \
    float vf = ((g & 1) ? m1 : m0) + __shfl_xor(w, 16);                     \
    vf += __shfl_xor(vf, 1);                                                \
    vf += __shfl_xor(vf, 2);                                                \
    vf += __shfl_xor(vf, 4);                                                \
    vf += __shfl_xor(vf, 8);                                                \
    if (cl == 0) y[(size_t)(ir)*4 + g] = vf;                                \
    sAcc += vf; qAcc += vf * vf;                                            \
  } while (0)

#define ROTATE()                                                            \
  do {                                                                      \
    balTailP = balTailN; jP = jN; cntP = cntN;                              \
    k0P = k0N; k1P = k1N; k2P = k2N; k3P = k3N;                             \
    g0P = g0N; g1P = g1N; g2P = g2N; g3P = g3N;                             \
  } while (0)

  if (rbeg < rend) {
    FRONT(rbeg);
    ROTATE();
    for (int i = rbeg + 1; i < rend; ++i) {
      FRONT(i);     // issue row i's gathers (latency hidden under BACK(i-1))
      BACK(i - 1);
      ROTATE();
    }
    BACK(rend - 1);
  }
#undef FRONT
#undef ACCD
#undef BACK
#undef ROTATE

  // sAcc/qAcc identical across the 16 lanes of each group; cl==0 writes
  if (cl == 0) {
    float* p = bnpart + (size_t)gwave * 8;
    p[g] = sAcc;
    p[4 + g] = qAcc;
  }
}

// ---------------------------------------------------------------- BN stat reduce -> scale/shift
__global__ void bn_reduce_kernel(const float* __restrict__ bnpart, int nparts,
                                 const float* __restrict__ gamma, const float* __restrict__ beta,
                                 float* __restrict__ scsh, int N) {
  __shared__ float red[256 * 8];
  int t = threadIdx.x;
  float S[8];
#pragma unroll
  for (int o = 0; o < 8; ++o) S[o] = 0.f;
  for (int i = t; i < nparts; i += 256) {
#pragma unroll
    for (int o = 0; o < 8; ++o) S[o] += bnpart[(size_t)i * 8 + o];
  }
#pragma unroll
  for (int o = 0; o < 8; ++o) red[t * 8 + o] = S[o];
  __syncthreads();
  for (int st = 128; st > 0; st >>= 1) {
    if (t < st) {
#pragma unroll
      for (int o = 0; o < 8; ++o) red[t * 8 + o] += red[(t + st) * 8 + o];
    }
    __syncthreads();
  }
  if (t == 0) {
    float invN = 1.f / (float)N;
#pragma unroll
    for (int o = 0; o < 4; ++o) {
      float mu = red[o] * invN;
      float var = red[4 + o] * invN - mu * mu;
      float sc = gamma[o] * rsqrtf(var + BN_EPS);
      scsh[o] = sc;
      scsh[4 + o] = beta[o] - mu * sc;
    }
  }
}

// ---------------------------------------------------------------- fused epilogue
__global__ __launch_bounds__(256) void final_kernel(
    const float* __restrict__ feats, const float* __restrict__ wgt,
    const float* __restrict__ y, const float* __restrict__ scsh,
    const float* __restrict__ c2, float* __restrict__ out, int N, int NPER) {
  int lane = threadIdx.x & 63;
  int gwave = blockIdx.x * (blockDim.x >> 6) + (threadIdx.x >> 6);
  int nwaves = gridDim.x * (blockDim.x >> 6);
  int rpw = (N + nwaves - 1) / nwaves;
  int rbeg = gwave * rpw, rend = min(N, rbeg + rpw);
  if (rbeg >= rend) return;
  float4 sc = *(const float4*)scsh;
  float4 sh = *(const float4*)(scsh + 4);
  float4 r0 = *(const float4*)(c2 + 0);
  float4 r1 = *(const float4*)(c2 + 4);
  float4 r2 = *(const float4*)(c2 + 8);
  float4 r3 = *(const float4*)(c2 + 12);
  int bB = min(rbeg / NPER, BATCHES - 1);
  int bEnd = (bB + 1) * NPER;
  float2 w = *(const float2*)(wgt + bB * C + 2 * lane);

  float4 yvN = *(const float4*)(y + (size_t)rbeg * 4);
  float2 fN = *(const float2*)(feats + (size_t)rbeg * C + 2 * lane);
  for (int i = rbeg; i < rend; ++i) {
    float4 yv = yvN;
    float2 f = fN;
    if (i + 1 < rend) {
      yvN = *(const float4*)(y + (size_t)(i + 1) * 4);
      fN = *(const float2*)(feats + (size_t)(i + 1) * C + 2 * lane);
    }
    if (i >= bEnd && bB < BATCHES - 1) {
      ++bB; bEnd += NPER;
      w = *(const float2*)(wgt + bB * C + 2 * lane);
    }
    float y0 = fmaxf(yv.x * sc.x + sh.x, 0.f);
    float y1 = fmaxf(yv.y * sc.y + sh.y, 0.f);
    float y2 = fmaxf(yv.z * sc.z + sh.z, 0.f);
    float y3 = fmaxf(yv.w * sc.w + sh.w, 0.f);
    float z0 = y0 * r0.x + y1 * r1.x + y2 * r2.x + y3 * r3.x;
    float z1 = y0 * r0.y + y1 * r1.y + y2 * r2.y + y3 * r3.y;
    float z2 = y0 * r0.z + y1 * r1.z + y2 * r2.z + y3 * r3.z;
    float z3 = y0 * r0.w + y1 * r1.w + y2 * r2.w + y3 * r3.w;
    float zm = fmaxf(fmaxf(z0, z1), fmaxf(z2, z3));
    float gate = 1.f / (1.f + expf(-zm));
    float g1 = 1.f + gate;
    float2 o2;
    o2.x = f.x * (1.f + w.x * g1);
    o2.y = f.y * (1.f + w.y * g1);
    *(float2*)(out + (size_t)i * C + 2 * lane) = o2;
  }
}

extern "C" void kernel_launch(void* const* d_in, const int* in_sizes, int n_in,
                              void* d_out, int out_size, void* d_ws, size_t ws_size,
                              hipStream_t stream) {
  const float* feats   = (const float*)d_in[0];
  const float* w1      = (const float*)d_in[1];
  const float* b1      = (const float*)d_in[2];
  const float* w2      = (const float*)d_in[3];
  const float* b2      = (const float*)d_in[4];
  const float* conv1w  = (const float*)d_in[5];
  const float* gamma   = (const float*)d_in[6];
  const float* beta    = (const float*)d_in[7];
  const float* c2      = (const float*)d_in[8];
  const int*   nbr_idx = (const int*)d_in[9];
  const void*  nbr_mask = d_in[10];
  int N = in_sizes[0] / C;
  int NPER = N / BATCHES;

  char* ws = (char*)d_ws;
  size_t off = 0;
  int* flag = (int*)(ws + off);        off += 16;
  float* psum = (float*)(ws + off);    off += (size_t)BATCHES * RA_BPB * C * 4;
  float* pmax = (float*)(ws + off);    off += (size_t)BATCHES * RA_BPB * C * 4;
  float* wgt  = (float*)(ws + off);    off += (size_t)BATCHES * C * 4;
  float* y    = (float*)(ws + off);    off += (size_t)N * 4 * 4;
  float* bnpart = (float*)(ws + off);  off += (size_t)NWAVES_CONV * 8 * 4;
  float* scsh = (float*)(ws + off);    off += 64;
  float* outp = (float*)d_out;

  hipMemsetAsync(flag, 0, sizeof(int), stream);
  reduceA_kernel<<<BATCHES * RA_BPB, 256, 0, stream>>>(
      feats, psum, pmax, (const unsigned int*)nbr_mask, flag, NPER);
  reduceB_mlp_kernel<<<BATCHES, 256, 0, stream>>>(psum, pmax, w1, b1, w2, b2, wgt, NPER);
  conv_kernel<<<CONV_BLOCKS, CONV_TPB, 0, stream>>>(feats, wgt, conv1w, nbr_idx, nbr_mask,
                                                    flag, y, bnpart, N, NPER);
  bn_reduce_kernel<<<1, 256, 0, stream>>>(bnpart, NWAVES_CONV, gamma, beta, scsh, N);
  final_kernel<<<2048, 256, 0, stream>>>(feats, wgt, y, scsh, c2, outp, N, NPER);
}

// Round 15
// 151.059 us; speedup vs baseline: 1.2875x; 1.0151x over previous
//
#include <hip/hip_runtime.h>

#define C 128
#define K 27
#define BATCHES 4
#define RA_BPB 512            // stage-A blocks per batch
#define CONV_BLOCKS 512       // 128 blocks per batch (batch-aligned mapping)
#define CONV_BPB (CONV_BLOCKS / BATCHES)
#define CONV_TPB 1024
#define NWAVES_CONV (CONV_BLOCKS * (CONV_TPB / 64))   // 8192
#define BN_EPS 1e-5f

typedef __attribute__((ext_vector_type(2))) __fp16 h2;
typedef __attribute__((ext_vector_type(8))) __fp16 h8;

// ---------------------------------------------------------------- stage A reduce + mask dtype probe
__global__ __launch_bounds__(256) void reduceA_kernel(
    const float* __restrict__ feats, float* __restrict__ psum,
    float* __restrict__ pmax, const unsigned int* __restrict__ mwords,
    int* __restrict__ flag, int NPER) {
  int base = blockIdx.x * 512;
  bool bad = false;
  bad |= (mwords[base + threadIdx.x] > 1u);
  bad |= (mwords[base + 256 + threadIdx.x] > 1u);
  if (__any(bad) && (threadIdx.x & 63) == 0) atomicOr(flag, 1);

  int b = blockIdx.x / RA_BPB, chunk = blockIdx.x % RA_BPB;
  int CH = (NPER + RA_BPB - 1) / RA_BPB;
  int r0 = b * NPER + chunk * CH;
  int r1 = min(b * NPER + NPER, r0 + CH);
  int g = threadIdx.x >> 5;   // 8 row groups
  int l = threadIdx.x & 31;   // lane -> channels 4l..4l+3
  float4 s = make_float4(0.f, 0.f, 0.f, 0.f);
  float4 m = make_float4(-INFINITY, -INFINITY, -INFINITY, -INFINITY);
  int i = r0 + g;
  for (; i + 8 < r1; i += 16) {
    float4 v1 = *(const float4*)(feats + (size_t)i * C + l * 4);
    float4 v2 = *(const float4*)(feats + (size_t)(i + 8) * C + l * 4);
    s.x += v1.x + v2.x; s.y += v1.y + v2.y;
    s.z += v1.z + v2.z; s.w += v1.w + v2.w;
    m.x = fmaxf(m.x, fmaxf(v1.x, v2.x)); m.y = fmaxf(m.y, fmaxf(v1.y, v2.y));
    m.z = fmaxf(m.z, fmaxf(v1.z, v2.z)); m.w = fmaxf(m.w, fmaxf(v1.w, v2.w));
  }
  if (i < r1) {
    float4 v = *(const float4*)(feats + (size_t)i * C + l * 4);
    s.x += v.x; s.y += v.y; s.z += v.z; s.w += v.w;
    m.x = fmaxf(m.x, v.x); m.y = fmaxf(m.y, v.y);
    m.z = fmaxf(m.z, v.z); m.w = fmaxf(m.w, v.w);
  }
  __shared__ float ssum[8][C], smax[8][C];
  *(float4*)&ssum[g][l * 4] = s;
  *(float4*)&smax[g][l * 4] = m;
  __syncthreads();
  if (threadIdx.x < C) {
    int c = threadIdx.x;
    float S = 0.f, M = -INFINITY;
#pragma unroll
    for (int gg = 0; gg < 8; ++gg) {
      S += ssum[gg][c];
      M = fmaxf(M, smax[gg][c]);
    }
    psum[(size_t)blockIdx.x * C + c] = S;
    pmax[(size_t)blockIdx.x * C + c] = M;
  }
}

// ---------------------------------------------------------------- stage B + channel MLP (fused)
__global__ __launch_bounds__(256) void reduceB_mlp_kernel(
    const float* __restrict__ psum, const float* __restrict__ pmax,
    const float* __restrict__ w1, const float* __restrict__ b1,
    const float* __restrict__ w2, const float* __restrict__ b2,
    float* __restrict__ wgt, int NPER) {
  int b = blockIdx.x;
  int g = threadIdx.x >> 5, l = threadIdx.x & 31;
  float4 s = make_float4(0.f, 0.f, 0.f, 0.f);
  float4 m = make_float4(-INFINITY, -INFINITY, -INFINITY, -INFINITY);
  for (int j = g; j < RA_BPB; j += 8) {
    size_t base = (size_t)(b * RA_BPB + j) * C + l * 4;
    float4 vs = *(const float4*)(psum + base);
    float4 vm = *(const float4*)(pmax + base);
    s.x += vs.x; s.y += vs.y; s.z += vs.z; s.w += vs.w;
    m.x = fmaxf(m.x, vm.x); m.y = fmaxf(m.y, vm.y);
    m.z = fmaxf(m.z, vm.z); m.w = fmaxf(m.w, vm.w);
  }
  __shared__ float ssum[8][C], smax[8][C];
  *(float4*)&ssum[g][l * 4] = s;
  *(float4*)&smax[g][l * 4] = m;
  __syncthreads();
  __shared__ float avgs[C], mxs[C];
  if (threadIdx.x < C) {
    int c = threadIdx.x;
    float S = 0.f, M = -INFINITY;
#pragma unroll
    for (int gg = 0; gg < 8; ++gg) {
      S += ssum[gg][c];
      M = fmaxf(M, smax[gg][c]);
    }
    avgs[c] = S / (float)NPER;
    mxs[c] = M;
  }
  __syncthreads();
  __shared__ float h1a[64], h1m[64];
  int t = threadIdx.x;
  if (t < 64) {
    float sa = b1[t], sm = b1[t];
    for (int c = 0; c < C; ++c) {
      float wv = w1[c * 64 + t];
      sa += avgs[c] * wv;
      sm += mxs[c] * wv;
    }
    h1a[t] = fmaxf(sa, 0.f);
    h1m[t] = fmaxf(sm, 0.f);
  }
  __syncthreads();
  if (t < C) {
    float za = b2[t], zm = b2[t];
    for (int h = 0; h < 64; ++h) {
      float wv = w2[h * C + t];
      za += h1a[h] * wv;
      zm += h1m[h] * wv;
    }
    float z = za + zm;
    wgt[b * C + t] = 1.f / (1.f + expf(-z));
  }
}

// ---------------------------------------------------------------- sparse 3x3x3 conv C->4 + BN partials
// One row per wave, 2 channels/lane, single-row ballot, depth-2 pipeline
// (R9/R11: >2 rows in flight inflates HBM FETCH 35-50% -> never).
// Batch-aligned blocks fold wr[b][c] into LDS f16 weights at staging (R13).
// Reduction: select-then-exchange + shfl_xor 1/2/4/8 (R13 proven; the R14
// DPP variant diverged under graph replay -> permanently dropped).
__global__ __launch_bounds__(CONV_TPB, 8) void conv_kernel(
    const float* __restrict__ feats, const float* __restrict__ wgt,
    const float* __restrict__ conv1_w, const int* __restrict__ nbr_idx,
    const void* __restrict__ nbr_mask, const int* __restrict__ flagp,
    float* __restrict__ y, float* __restrict__ bnpart, int N, int NPER) {
  int bat = blockIdx.x / CONV_BPB;
  const float* wgtRow = wgt + bat * C;
  __shared__ __align__(16) h8 wlds[K * 64];  // 27648 B
  int tid = threadIdx.x;
  for (int e = tid; e < K * 64; e += CONV_TPB) {
    int l = e & 63;
    float wa = wgtRow[2 * l], wb = wgtRow[2 * l + 1];
    float4 A = ((const float4*)conv1_w)[e * 2];
    float4 B = ((const float4*)conv1_w)[e * 2 + 1];
    h8 w;
    h2 p;
    p = __builtin_amdgcn_cvt_pkrtz(A.x * wa, B.x * wb); w[0] = p[0]; w[1] = p[1];
    p = __builtin_amdgcn_cvt_pkrtz(A.y * wa, B.y * wb); w[2] = p[0]; w[3] = p[1];
    p = __builtin_amdgcn_cvt_pkrtz(A.z * wa, B.z * wb); w[4] = p[0]; w[5] = p[1];
    p = __builtin_amdgcn_cvt_pkrtz(A.w * wa, B.w * wb); w[6] = p[0]; w[7] = p[1];
    wlds[e] = w;
  }
  __syncthreads();

  int lane = tid & 63;
  int g = lane >> 4, cl = lane & 15;
  int gwave = blockIdx.x * (CONV_TPB / 64) + (tid >> 6);
  int wb = (blockIdx.x % CONV_BPB) * (CONV_TPB / 64) + (tid >> 6);  // wave within batch
  int wavesPerBatch = CONV_BPB * (CONV_TPB / 64);
  int rpw = (NPER + wavesPerBatch - 1) / wavesPerBatch;
  int rbeg = bat * NPER + wb * rpw;
  int rend = min(bat * NPER + NPER, rbeg + rpw);
  bool byteMode = (*flagp != 0);
  const unsigned char* mb = (const unsigned char*)nbr_mask;
  const int* mi = (const int*)nbr_mask;

  // prime mask/idx for row rbeg
  bool mk = false;
  int jl = 0;
  if (rbeg < rend && lane < K) {
    size_t e = (size_t)rbeg * K + lane;
    mk = byteMode ? (mb[e] != 0) : (mi[e] != 0);
    jl = nbr_idx[e];
  }

  float sAcc = 0.f, qAcc = 0.f;  // BN partials for this lane's output group g

  // pipeline registers (N = being fetched, P = ready for compute)
  unsigned balTailN = 0, balTailP = 0;
  int jN = 0, jP = 0, cntN = 0, cntP = 0;
  int k0N = 0, k1N = 0, k2N = 0, k3N = 0, k0P = 0, k1P = 0, k2P = 0, k3P = 0;
  float2 g0N = make_float2(0, 0), g1N = g0N, g2N = g0N, g3N = g0N;
  float2 g0P = g0N, g1P = g0N, g2P = g0N, g3P = g0N;

#define FRONT(iF)                                                           \
  do {                                                                      \
    unsigned bb = (unsigned)__ballot(mk);                                   \
    jN = jl;                                                                \
    mk = false;                                                             \
    if ((iF) + 1 < rend && lane < K) {                                      \
      size_t e = (size_t)((iF) + 1) * K + lane;                             \
      mk = byteMode ? (mb[e] != 0) : (mi[e] != 0);                          \
      jl = nbr_idx[e];                                                      \
    }                                                                       \
    cntN = __popc(bb);                                                      \
    k0N = __ffs(bb) - 1; bb &= bb - 1;                                      \
    k1N = __ffs(bb) - 1; bb &= bb - 1;                                      \
    k2N = __ffs(bb) - 1; bb &= bb - 1;                                      \
    k3N = __ffs(bb) - 1; bb &= bb - 1;                                      \
    balTailN = bb;                                                          \
    int j0 = __shfl(jN, k0N & 63);                                          \
    int j1 = __shfl(jN, k1N & 63);                                          \
    int j2 = __shfl(jN, k2N & 63);                                          \
    int j3 = __shfl(jN, k3N & 63);                                          \
    if (cntN > 0) g0N = *(const float2*)(feats + (size_t)j0 * C + 2 * lane);\
    if (cntN > 1) g1N = *(const float2*)(feats + (size_t)j1 * C + 2 * lane);\
    if (cntN > 2) g2N = *(const float2*)(feats + (size_t)j2 * C + 2 * lane);\
    if (cntN > 3) g3N = *(const float2*)(feats + (size_t)j3 * C + 2 * lane);\
  } while (0)

#define ACCD(ff, kk)                                                        \
  {                                                                         \
    h2 fp = __builtin_amdgcn_cvt_pkrtz(ff.x, ff.y);                         \
    h8 w = wlds[(kk)*64 + lane];                                            \
    h2 w0 = __builtin_shufflevector(w, w, 0, 1);                            \
    h2 w1 = __builtin_shufflevector(w, w, 2, 3);                            \
    h2 w2 = __builtin_shufflevector(w, w, 4, 5);                            \
    h2 w3 = __builtin_shufflevector(w, w, 6, 7);                            \
    a0 = __builtin_amdgcn_fdot2(fp, w0, a0, false);                         \
    a1 = __builtin_amdgcn_fdot2(fp, w1, a1, false);                         \
    a2 = __builtin_amdgcn_fdot2(fp, w2, a2, false);                         \
    a3 = __builtin_amdgcn_fdot2(fp, w3, a3, false);                         \
  }

#define BACK(ir)                                                            \
  do {                                                                      \
    float a0 = 0, a1 = 0, a2 = 0, a3 = 0;                                   \
    if (cntP > 0) ACCD(g0P, k0P)                                            \
    if (cntP > 1) ACCD(g1P, k1P)                                            \
    if (cntP > 2) ACCD(g2P, k2P)                                            \
    if (cntP > 3) ACCD(g3P, k3P)                                            \
    unsigned bt = balTailP;                                                 \
    while (bt) {                                                            \
      int kk = __ffs(bt) - 1; bt &= bt - 1;                                 \
      int jj = __shfl(jP, kk);                                              \
      float2 f = *(const float2*)(feats + (size_t)jj * C + 2 * lane);       \
      ACCD(f, kk)                                                           \
    }                                                                       \
    float u = (g < 2) ? a2 : a0;                                            \
    float vv = (g < 2) ? a3 : a1;                                           \
    float m0 = ((g < 2) ? a0 : a2) + __shfl_xor(u, 32);                     \
    float m1 = ((g < 2) ? a1 : a3) + __shfl_xor(vv, 32);                    \
    float w = (g & 1) ? m0 : m1;                                            \
    float vf = ((g & 1) ? m1 : m0) + __shfl_xor(w, 16);                     \
    vf += __shfl_xor(vf, 1);                                                \
    vf += __shfl_xor(vf, 2);                                                \
    vf += __shfl_xor(vf, 4);                                                \
    vf += __shfl_xor(vf, 8);                                                \
    if (cl == 0) y[(size_t)(ir)*4 + g] = vf;                                \
    sAcc += vf; qAcc += vf * vf;                                            \
  } while (0)

#define ROTATE()                                                            \
  do {                                                                      \
    balTailP = balTailN; jP = jN; cntP = cntN;                              \
    k0P = k0N; k1P = k1N; k2P = k2N; k3P = k3N;                             \
    g0P = g0N; g1P = g1N; g2P = g2N; g3P = g3N;                             \
  } while (0)

  if (rbeg < rend) {
    FRONT(rbeg);
    ROTATE();
    for (int i = rbeg + 1; i < rend; ++i) {
      FRONT(i);     // issue row i's gathers (latency hidden under BACK(i-1))
      BACK(i - 1);
      ROTATE();
    }
    BACK(rend - 1);
  }
#undef FRONT
#undef ACCD
#undef BACK
#undef ROTATE

  // sAcc/qAcc identical across the 16 lanes of each group; cl==0 writes
  if (cl == 0) {
    float* p = bnpart + (size_t)gwave * 8;
    p[g] = sAcc;
    p[4 + g] = qAcc;
  }
}

// ---------------------------------------------------------------- BN stat reduce -> scale/shift
__global__ void bn_reduce_kernel(const float* __restrict__ bnpart, int nparts,
                                 const float* __restrict__ gamma, const float* __restrict__ beta,
                                 float* __restrict__ scsh, int N) {
  __shared__ float red[256 * 8];
  int t = threadIdx.x;
  float S[8];
#pragma unroll
  for (int o = 0; o < 8; ++o) S[o] = 0.f;
  for (int i = t; i < nparts; i += 256) {
#pragma unroll
    for (int o = 0; o < 8; ++o) S[o] += bnpart[(size_t)i * 8 + o];
  }
#pragma unroll
  for (int o = 0; o < 8; ++o) red[t * 8 + o] = S[o];
  __syncthreads();
  for (int st = 128; st > 0; st >>= 1) {
    if (t < st) {
#pragma unroll
      for (int o = 0; o < 8; ++o) red[t * 8 + o] += red[(t + st) * 8 + o];
    }
    __syncthreads();
  }
  if (t == 0) {
    float invN = 1.f / (float)N;
#pragma unroll
    for (int o = 0; o < 4; ++o) {
      float mu = red[o] * invN;
      float var = red[4 + o] * invN - mu * mu;
      float sc = gamma[o] * rsqrtf(var + BN_EPS);
      scsh[o] = sc;
      scsh[4 + o] = beta[o] - mu * sc;
    }
  }
}

// ---------------------------------------------------------------- fused epilogue
// Two rows per wave: half-wave (32 lanes) x float4 = one 512B row each.
// Pure streaming (no cross-lane ops, no shared state). Pairs never straddle
// a batch (NPER even). 16B/lane coalescing.
__global__ __launch_bounds__(256) void final_kernel(
    const float* __restrict__ feats, const float* __restrict__ wgt,
    const float* __restrict__ y, const float* __restrict__ scsh,
    const float* __restrict__ c2, float* __restrict__ out, int N, int NPER) {
  int lane = threadIdx.x & 63;
  int half = lane >> 5;       // 0: even row, 1: odd row of the pair
  int hl = lane & 31;         // channels 4*hl..4*hl+3
  int gwave = blockIdx.x * (blockDim.x >> 6) + (threadIdx.x >> 6);
  int nwaves = gridDim.x * (blockDim.x >> 6);
  int P = (N + 1) >> 1;
  int ppw = (P + nwaves - 1) / nwaves;
  int pbeg = gwave * ppw, pend = min(P, pbeg + ppw);
  if (pbeg >= pend) return;
  float4 sc = *(const float4*)scsh;
  float4 sh = *(const float4*)(scsh + 4);
  float4 r0 = *(const float4*)(c2 + 0);
  float4 r1 = *(const float4*)(c2 + 4);
  float4 r2 = *(const float4*)(c2 + 8);
  float4 r3 = *(const float4*)(c2 + 12);
  int bB = min((2 * pbeg) / NPER, BATCHES - 1);
  int bEnd = (bB + 1) * NPER;
  float4 w = *(const float4*)(wgt + bB * C + hl * 4);

  int i0 = 2 * pbeg + half;
  float4 yvN = make_float4(0, 0, 0, 0), fN = yvN;
  if (i0 < N) {
    yvN = *(const float4*)(y + (size_t)i0 * 4);
    fN = *(const float4*)(feats + (size_t)i0 * C + hl * 4);
  }
  for (int p = pbeg; p < pend; ++p) {
    int i = 2 * p + half;
    float4 yv = yvN;
    float4 f = fN;
    int inext = 2 * (p + 1) + half;
    if (p + 1 < pend && inext < N) {
      yvN = *(const float4*)(y + (size_t)inext * 4);
      fN = *(const float4*)(feats + (size_t)inext * C + hl * 4);
    }
    if (2 * p >= bEnd && bB < BATCHES - 1) {
      ++bB; bEnd += NPER;
      w = *(const float4*)(wgt + bB * C + hl * 4);
    }
    if (i < N) {
      float y0 = fmaxf(yv.x * sc.x + sh.x, 0.f);
      float y1 = fmaxf(yv.y * sc.y + sh.y, 0.f);
      float y2 = fmaxf(yv.z * sc.z + sh.z, 0.f);
      float y3 = fmaxf(yv.w * sc.w + sh.w, 0.f);
      float z0 = y0 * r0.x + y1 * r1.x + y2 * r2.x + y3 * r3.x;
      float z1 = y0 * r0.y + y1 * r1.y + y2 * r2.y + y3 * r3.y;
      float z2 = y0 * r0.z + y1 * r1.z + y2 * r2.z + y3 * r3.z;
      float z3 = y0 * r0.w + y1 * r1.w + y2 * r2.w + y3 * r3.w;
      float zm = fmaxf(fmaxf(z0, z1), fmaxf(z2, z3));
      float gate = 1.f / (1.f + expf(-zm));
      float g1 = 1.f + gate;
      float4 o;
      o.x = f.x * (1.f + w.x * g1);
      o.y = f.y * (1.f + w.y * g1);
      o.z = f.z * (1.f + w.z * g1);
      o.w = f.w * (1.f + w.w * g1);
      *(float4*)(out + (size_t)i * C + hl * 4) = o;
    }
  }
}

extern "C" void kernel_launch(void* const* d_in, const int* in_sizes, int n_in,
                              void* d_out, int out_size, void* d_ws, size_t ws_size,
                              hipStream_t stream) {
  const float* feats   = (const float*)d_in[0];
  const float* w1      = (const float*)d_in[1];
  const float* b1      = (const float*)d_in[2];
  const float* w2      = (const float*)d_in[3];
  const float* b2      = (const float*)d_in[4];
  const float* conv1w  = (const float*)d_in[5];
  const float* gamma   = (const float*)d_in[6];
  const float* beta    = (const float*)d_in[7];
  const float* c2      = (const float*)d_in[8];
  const int*   nbr_idx = (const int*)d_in[9];
  const void*  nbr_mask = d_in[10];
  int N = in_sizes[0] / C;
  int NPER = N / BATCHES;

  char* ws = (char*)d_ws;
  size_t off = 0;
  int* flag = (int*)(ws + off);        off += 16;
  float* psum = (float*)(ws + off);    off += (size_t)BATCHES * RA_BPB * C * 4;
  float* pmax = (float*)(ws + off);    off += (size_t)BATCHES * RA_BPB * C * 4;
  float* wgt  = (float*)(ws + off);    off += (size_t)BATCHES * C * 4;
  float* y    = (float*)(ws + off);    off += (size_t)N * 4 * 4;
  float* bnpart = (float*)(ws + off);  off += (size_t)NWAVES_CONV * 8 * 4;
  float* scsh = (float*)(ws + off);    off += 64;
  float* outp = (float*)d_out;

  hipMemsetAsync(flag, 0, sizeof(int), stream);
  reduceA_kernel<<<BATCHES * RA_BPB, 256, 0, stream>>>(
      feats, psum, pmax, (const unsigned int*)nbr_mask, flag, NPER);
  reduceB_mlp_kernel<<<BATCHES, 256, 0, stream>>>(psum, pmax, w1, b1, w2, b2, wgt, NPER);
  conv_kernel<<<CONV_BLOCKS, CONV_TPB, 0, stream>>>(feats, wgt, conv1w, nbr_idx, nbr_mask,
                                                    flag, y, bnpart, N, NPER);
  bn_reduce_kernel<<<1, 256, 0, stream>>>(bnpart, NWAVES_CONV, gamma, beta, scsh, N);
  final_kernel<<<2048, 256, 0, stream>>>(feats, wgt, y, scsh, c2, outp, N, NPER);
}